// Round 3
// baseline (240.905 us; speedup 1.0000x reference)
//
#include <hip/hip_runtime.h>

// Adder2D: out[n,h,w,f] = bias[f] - sum_{i,j,c} |x[n,h+i-1,w+j-1,c] - K[i,j,c,f]|
// x: [32,32,32,128] f32, K: [3,3,128,128] f32, bias: [128] f32, out: [32,32,32,128] f32.
// VALU-bound (no MFMA possible: |x-w| is not bilinear).
// Inner op: 3 full-rate packed-f16 VALU per 2 element-ops:
//   v_pk_add_f16 (x + (-w), W staged pre-negated)  -> diff
//   v_and_b32 0x7fff7fff                            -> packed abs
//   v_pk_add_f16 (f16 pair accumulate)              -> acc
// f16 pair-accumulators are dumped to f32 once per 64-channel chunk (18x):
// chunk sums ~72, ulp 0.0625 -> total f16-accum error ~±1 vs threshold 28.96.
// NO v_dot2_f32_f16: round-2 counters showed it costs ~4x a full-rate op.

typedef _Float16 v2h __attribute__((ext_vector_type(2)));
typedef float    v4f __attribute__((ext_vector_type(4)));

#define CC 128
#define FF 128
#define KC2 32          // channel-pairs per chunk (64 channels)
#define SX 34           // Xs row stride in half2-words (32 px + 2 pad)
#define SW 128          // Ws row stride in half2-words

static __device__ __forceinline__ unsigned pack2(float a, float b) {
    return __builtin_bit_cast(unsigned, __builtin_amdgcn_cvt_pkrtz(a, b));
}
static __device__ __forceinline__ unsigned pack2n(float a, float b) {
    // negation folds into VOP3 input modifiers of v_cvt_pkrtz_f16_f32: free
    return __builtin_bit_cast(unsigned, __builtin_amdgcn_cvt_pkrtz(-a, -b));
}

__global__ __launch_bounds__(256, 4)
void adder2d_kernel(const float* __restrict__ x,
                    const float* __restrict__ kern,
                    const float* __restrict__ bias,
                    float* __restrict__ out)
{
    __shared__ unsigned Xs[KC2 * SX];    //  4.3 KB: [kk2][px]  (x[c],x[c+1]) packed f16
    __shared__ unsigned Wsm[KC2 * SW];   // 16.4 KB: [kk2][f]   (-w[c][f],-w[c+1][f]) packed f16

    const int t  = threadIdx.x;
    const int r  = blockIdx.x;      // 0..1023 = global row id
    const int n  = r >> 5;          // image
    const int h  = r & 31;          // row within image

    // compute mapping: 16 pixel-groups (2 px) x 16 filter-groups (8 f)
    const int pg = t >> 4;
    const int fg = t & 15;
    const int f0 = fg << 3;
    const int p0 = pg << 1;

    float    accf[2][8];            // f32 totals
    unsigned acc2[2][8];            // packed-f16 per-chunk partials
#pragma unroll
    for (int pi = 0; pi < 2; ++pi)
#pragma unroll
        for (int fi = 0; fi < 8; ++fi) { accf[pi][fi] = 0.f; acc2[pi][fi] = 0u; }

    // X staging mapping: thread loads 8 consecutive channels of one pixel
    const int sp = t >> 3;          // pixel 0..31
    const int sa = t & 7;           // channel-octet 0..7 (coalesced)

    for (int ij = 0; ij < 9; ++ij) {
        const int di = ij / 3 - 1;
        const int dj = ij % 3 - 1;
        const int hh = h + di;
        const bool rowok = ((unsigned)hh) < 32u;
        const int  wx = sp + dj;
        const bool xok = rowok && (((unsigned)wx) < 32u);
        const float* xsrc = x + (((n * 32 + hh) * 32 + wx) * CC) + (sa << 3);

        for (int cs = 0; cs < 2; ++cs) {
            const int c0 = cs << 6;
            __syncthreads();   // protect LDS from previous chunk's readers

            // ---- stage X: 32 px x 64 ch; zeros for OOB => |0-w| like zero-pad ----
            {
                v4f g0 = {0.f, 0.f, 0.f, 0.f}, g1 = {0.f, 0.f, 0.f, 0.f};
                if (xok) {
                    const float* s = xsrc + c0;
                    g0 = *(const v4f*)s;
                    g1 = *(const v4f*)(s + 4);
                }
                const int kb = sa << 2;
                Xs[(kb + 0) * SX + sp] = pack2(g0.x, g0.y);
                Xs[(kb + 1) * SX + sp] = pack2(g0.z, g0.w);
                Xs[(kb + 2) * SX + sp] = pack2(g1.x, g1.y);
                Xs[(kb + 3) * SX + sp] = pack2(g1.z, g1.w);
            }

            // ---- stage W (pre-negated): 32 kk2 x 128 f, coalesced ----
#pragma unroll
            for (int pass = 0; pass < 4; ++pass) {
                const int idx = (pass << 8) + t;
                const int kk2 = idx >> 5;          // 0..31
                const int f4  = (idx & 31) << 2;   // 0..124
                const float* s = kern + ((ij * CC + c0 + (kk2 << 1)) * FF) + f4;
                v4f ga = *(const v4f*)s;           // channel c
                v4f gb = *(const v4f*)(s + FF);    // channel c+1
                uint4 wq;
                wq.x = pack2n(ga.x, gb.x);
                wq.y = pack2n(ga.y, gb.y);
                wq.z = pack2n(ga.z, gb.z);
                wq.w = pack2n(ga.w, gb.w);
                *(uint4*)&Wsm[kk2 * SW + f4] = wq;
            }
            __syncthreads();

            // ---- compute: per kk2: 3 LDS reads + 16 outputs * 3 pk-VALU ----
#pragma unroll 8
            for (int kk2 = 0; kk2 < KC2; ++kk2) {
                const uint2 xv = *(const uint2*)&Xs[kk2 * SX + p0];
                const uint4 wa = *(const uint4*)&Wsm[kk2 * SW + f0];
                const uint4 wb = *(const uint4*)&Wsm[kk2 * SW + f0 + 4];
                const unsigned w8[8] = {wa.x, wa.y, wa.z, wa.w, wb.x, wb.y, wb.z, wb.w};
#pragma unroll
                for (int pi = 0; pi < 2; ++pi) {
                    const unsigned xp = (pi == 0) ? xv.x : xv.y;
#pragma unroll
                    for (int fi = 0; fi < 8; ++fi) {
                        unsigned s;
                        asm("v_pk_add_f16 %0, %1, %2" : "=v"(s) : "v"(xp), "v"(w8[fi]));
                        const unsigned a = s & 0x7FFF7FFFu;      // packed |.|
                        asm("v_pk_add_f16 %0, %1, %0" : "+v"(acc2[pi][fi]) : "v"(a));
                    }
                }
            }

            // ---- dump packed-f16 partials to f32 (per 64-ch chunk) ----
#pragma unroll
            for (int pi = 0; pi < 2; ++pi)
#pragma unroll
                for (int fi = 0; fi < 8; ++fi) {
                    const v2h ah = __builtin_bit_cast(v2h, acc2[pi][fi]);
                    accf[pi][fi] += (float)ah.x + (float)ah.y;
                    acc2[pi][fi] = 0u;
                }
        }
    }

    // ---- epilogue: out = bias - acc ----
    const v4f b0 = *(const v4f*)(bias + f0);
    const v4f b1 = *(const v4f*)(bias + f0 + 4);
#pragma unroll
    for (int pi = 0; pi < 2; ++pi) {
        float* dst = out + ((r * 32 + p0 + pi) * FF) + f0;
        v4f o0, o1;
        o0.x = b0.x - accf[pi][0];
        o0.y = b0.y - accf[pi][1];
        o0.z = b0.z - accf[pi][2];
        o0.w = b0.w - accf[pi][3];
        o1.x = b1.x - accf[pi][4];
        o1.y = b1.y - accf[pi][5];
        o1.z = b1.z - accf[pi][6];
        o1.w = b1.w - accf[pi][7];
        *(v4f*)dst = o0;
        *(v4f*)(dst + 4) = o1;
    }
}

extern "C" void kernel_launch(void* const* d_in, const int* in_sizes, int n_in,
                              void* d_out, int out_size, void* d_ws, size_t ws_size,
                              hipStream_t stream) {
    const float* x    = (const float*)d_in[0];
    const float* kern = (const float*)d_in[1];
    const float* bias = (const float*)d_in[2];
    float* out = (float*)d_out;
    dim3 grid(1024);   // 32 images * 32 rows
    dim3 block(256);
    adder2d_kernel<<<grid, block, 0, stream>>>(x, kern, bias, out);
}

// Round 4
// 185.667 us; speedup vs baseline: 1.2975x; 1.2975x over previous
//
#include <hip/hip_runtime.h>

// Adder2D: out[n,h,w,f] = bias[f] - sum_{ij,c} |x[..,c] - K[ij,c,f]|
// Identity: sum |x-w| = 2*sum max(x,w) - sum x - sum w.
//   - sum_x over the 9-tap x 128-ch receptive field: precomputed per-pixel
//     channel sums Sx[32768], 3x3-combined per row in the main kernel.
//   - sum_w per filter: folded into biasW[f] = bias[f] + sum_{ij,c} K[ij,c,f].
// Inner loop: 2 full-rate-packed instrs per channel-PAIR:
//   v_pk_max_f16 + v_pk_add_f16   (abs and subtract eliminated)
// f16 pair-accumulators dumped to f32 per 64-ch chunk (18x).
// W LDS layout XOR-swizzled at 16B units (u ^= u>>3): read bank-alias 4-way -> 2-way.

typedef _Float16 v2h  __attribute__((ext_vector_type(2)));
typedef __fp16   v2hb __attribute__((ext_vector_type(2)));
typedef float    v4f  __attribute__((ext_vector_type(4)));

#define CC 128
#define FF 128
#define KC2 32          // channel-pairs per chunk (64 channels)
#define SX 34           // Xs row stride in words (32 px + 2 pad)

static __device__ __forceinline__ unsigned pack2(float a, float b) {
    return __builtin_bit_cast(unsigned, __builtin_amdgcn_cvt_pkrtz(a, b));
}

// ---------- precompute: Sx[px] = sum_c x[px,c];  biasW[f] = bias[f]+sum K[:,f] ----------
__global__ __launch_bounds__(256)
void precompute_kernel(const float* __restrict__ x,
                       const float* __restrict__ kern,
                       const float* __restrict__ bias,
                       float* __restrict__ Sx,      // 32768 floats
                       float* __restrict__ biasW)   // 128 floats
{
    const int t = threadIdx.x;
    const int b = blockIdx.x;
    if (b < 512) {
        // per-pixel channel sum: 4 threads/pixel, coalesced v4f reads
        const int px = (b << 6) + (t >> 2);
        const int q  = t & 3;
        const float* s = x + px * CC + (q << 5);
        float acc = 0.f;
#pragma unroll
        for (int k = 0; k < 8; ++k) {
            v4f v = *(const v4f*)(s + (k << 2));
            acc += v.x + v.y + v.z + v.w;
        }
        acc += __shfl_xor(acc, 1);
        acc += __shfl_xor(acc, 2);
        if (q == 0) Sx[px] = acc;
    } else {
        // column sums of kern [1152][128], coalesced v4f + LDS transpose-reduce
        __shared__ v4f red4[256];
        v4f acc = {0.f, 0.f, 0.f, 0.f};
        const int c4 = t & 31;             // which v4f-column (4 filters)
#pragma unroll 8
        for (int i = 0; i < 144; ++i) {
            const int row = (i << 3) + (t >> 5);
            acc += *(const v4f*)(kern + row * FF + (c4 << 2));
        }
        red4[t] = acc;
        __syncthreads();
        if (t < 128) {
            const int u = t >> 2, e = t & 3;
            float s = 0.f;
#pragma unroll
            for (int j = 0; j < 8; ++j) s += red4[u + (j << 5)][e];
            biasW[t] = bias[t] + s;
        }
    }
}

// -------------------------------- main kernel --------------------------------
__global__ __launch_bounds__(256, 4)
void adder2d_kernel(const float* __restrict__ x,
                    const float* __restrict__ kern,
                    const float* __restrict__ biasW,
                    const float* __restrict__ Sx,
                    float* __restrict__ out)
{
    __shared__ unsigned Xs[KC2 * SX];     //  4.3 KB: [kk2][px]  (x[c],x[c+1]) f16-pair
    __shared__ unsigned Wsm[KC2 * 128];   // 16.4 KB: [kk2][swizzled f-unit] f16-pair
    __shared__ float    s3arr[34];        // 3-row column sums, +1 halo each side

    const int t  = threadIdx.x;
    const int r  = blockIdx.x;      // 0..1023 = global row id
    const int n  = r >> 5;          // image
    const int h  = r & 31;          // row within image

    // compute mapping: 16 pixel-groups (2 px) x 16 filter-groups (8 f)
    const int pg = t >> 4;
    const int fg = t & 15;
    const int f0 = fg << 3;
    const int p0 = pg << 1;
    // swizzled W read offsets (16B units, u' = u ^ (u>>3); per-thread constants)
    const int wu1 = (((fg << 1)     ^ (fg >> 2)) << 2);
    const int wu2 = ((((fg << 1)|1) ^ (fg >> 2)) << 2);

    // prologue: 3-row sums of Sx for SAME-pad 3x3 (row-OOB -> 0)
    if (t < 32) {
        float s3 = 0.f;
#pragma unroll
        for (int di = -1; di <= 1; ++di) {
            const int hh = h + di;
            if (0 <= hh && hh < 32) s3 += Sx[(n * 32 + hh) * 32 + t];
        }
        s3arr[t + 1] = s3;
    }
    if (t == 0) { s3arr[0] = 0.f; s3arr[33] = 0.f; }

    float    accf[2][8];
    unsigned acc2[2][8];
#pragma unroll
    for (int pi = 0; pi < 2; ++pi)
#pragma unroll
        for (int fi = 0; fi < 8; ++fi) { accf[pi][fi] = 0.f; acc2[pi][fi] = 0u; }

    // X staging mapping: thread loads 8 consecutive channels of one pixel
    const int sp = t >> 3;          // pixel 0..31
    const int sa = t & 7;           // channel-octet 0..7

    for (int ij = 0; ij < 9; ++ij) {
        const int di = ij / 3 - 1;
        const int dj = ij % 3 - 1;
        const int hh = h + di;
        const bool rowok = ((unsigned)hh) < 32u;
        const int  wx = sp + dj;
        const bool xok = rowok && (((unsigned)wx) < 32u);
        const float* xsrc = x + (((n * 32 + hh) * 32 + wx) * CC) + (sa << 3);

        for (int cs = 0; cs < 2; ++cs) {
            const int c0 = cs << 6;
            __syncthreads();   // protect LDS from previous chunk's readers

            // ---- stage X: zeros for OOB (=> max(0,w); Sx/SW terms account) ----
            {
                v4f g0 = {0.f, 0.f, 0.f, 0.f}, g1 = {0.f, 0.f, 0.f, 0.f};
                if (xok) {
                    const float* s = xsrc + c0;
                    g0 = *(const v4f*)s;
                    g1 = *(const v4f*)(s + 4);
                }
                const int kb = sa << 2;
                Xs[(kb + 0) * SX + sp] = pack2(g0.x, g0.y);
                Xs[(kb + 1) * SX + sp] = pack2(g0.z, g0.w);
                Xs[(kb + 2) * SX + sp] = pack2(g1.x, g1.y);
                Xs[(kb + 3) * SX + sp] = pack2(g1.z, g1.w);
            }

            // ---- stage W (swizzled 16B units): 32 kk2 x 128 f ----
#pragma unroll
            for (int pass = 0; pass < 4; ++pass) {
                const int idx = (pass << 8) + t;
                const int kk2 = idx >> 5;          // 0..31
                const int u   = idx & 31;          // 16B unit = 4 filters
                const int up  = u ^ (u >> 3);      // swizzle
                const float* s = kern + ((ij * CC + c0 + (kk2 << 1)) * FF) + (u << 2);
                v4f ga = *(const v4f*)s;           // channel c
                v4f gb = *(const v4f*)(s + FF);    // channel c+1
                uint4 wq;
                wq.x = pack2(ga.x, gb.x);
                wq.y = pack2(ga.y, gb.y);
                wq.z = pack2(ga.z, gb.z);
                wq.w = pack2(ga.w, gb.w);
                *(uint4*)&Wsm[(kk2 << 7) + (up << 2)] = wq;
            }
            __syncthreads();

            // ---- compute: per kk2: 3 LDS reads + 16 outputs * 2 pk-VALU ----
#pragma unroll 8
            for (int kk2 = 0; kk2 < KC2; ++kk2) {
                const uint2 xv = *(const uint2*)&Xs[kk2 * SX + p0];
                const uint4 wa = *(const uint4*)&Wsm[(kk2 << 7) + wu1];
                const uint4 wb = *(const uint4*)&Wsm[(kk2 << 7) + wu2];
                const unsigned w8[8] = {wa.x, wa.y, wa.z, wa.w, wb.x, wb.y, wb.z, wb.w};
#pragma unroll
                for (int pi = 0; pi < 2; ++pi) {
                    const unsigned xp = (pi == 0) ? xv.x : xv.y;
#pragma unroll
                    for (int fi = 0; fi < 8; ++fi) {
                        unsigned m;
                        asm("v_pk_max_f16 %0, %1, %2" : "=v"(m) : "v"(xp), "v"(w8[fi]));
                        asm("v_pk_add_f16 %0, %1, %0" : "+v"(acc2[pi][fi]) : "v"(m));
                    }
                }
            }

            // ---- dump packed-f16 partials to f32 (per 64-ch chunk) ----
#pragma unroll
            for (int pi = 0; pi < 2; ++pi)
#pragma unroll
                for (int fi = 0; fi < 8; ++fi) {
#if __has_builtin(__builtin_amdgcn_fdot2)
                    const v2hb av = __builtin_bit_cast(v2hb, acc2[pi][fi]);
                    const v2hb ones = {(__fp16)1.0f, (__fp16)1.0f};
                    accf[pi][fi] = __builtin_amdgcn_fdot2(av, ones, accf[pi][fi], false);
#else
                    const v2h ah = __builtin_bit_cast(v2h, acc2[pi][fi]);
                    accf[pi][fi] += (float)ah.x + (float)ah.y;
#endif
                    acc2[pi][fi] = 0u;
                }
        }
    }

    // ---- epilogue: out = biasW + S9 - 2*sum(max) ----
    const v4f b0 = *(const v4f*)(biasW + f0);
    const v4f b1 = *(const v4f*)(biasW + f0 + 4);
#pragma unroll
    for (int pi = 0; pi < 2; ++pi) {
        const float s9 = s3arr[p0 + pi] + s3arr[p0 + pi + 1] + s3arr[p0 + pi + 2];
        float* dst = out + ((r * 32 + p0 + pi) * FF) + f0;
        v4f o0, o1;
        o0.x = fmaf(-2.f, accf[pi][0], b0.x + s9);
        o0.y = fmaf(-2.f, accf[pi][1], b0.y + s9);
        o0.z = fmaf(-2.f, accf[pi][2], b0.z + s9);
        o0.w = fmaf(-2.f, accf[pi][3], b0.w + s9);
        o1.x = fmaf(-2.f, accf[pi][4], b1.x + s9);
        o1.y = fmaf(-2.f, accf[pi][5], b1.y + s9);
        o1.z = fmaf(-2.f, accf[pi][6], b1.z + s9);
        o1.w = fmaf(-2.f, accf[pi][7], b1.w + s9);
        *(v4f*)dst = o0;
        *(v4f*)(dst + 4) = o1;
    }
}

extern "C" void kernel_launch(void* const* d_in, const int* in_sizes, int n_in,
                              void* d_out, int out_size, void* d_ws, size_t ws_size,
                              hipStream_t stream) {
    const float* x    = (const float*)d_in[0];
    const float* kern = (const float*)d_in[1];
    const float* bias = (const float*)d_in[2];
    float* out   = (float*)d_out;
    float* Sx    = (float*)d_ws;          // 32768 floats
    float* biasW = Sx + 32768;            // 128 floats  (needs 131584 B of ws)

    precompute_kernel<<<513, 256, 0, stream>>>(x, kern, bias, Sx, biasW);
    adder2d_kernel<<<1024, 256, 0, stream>>>(x, kern, biasW, Sx, out);
}